// Round 9
// baseline (205.329 us; speedup 1.0000x reference)
//
#include <hip/hip_runtime.h>
#include <math.h>

#define NTHREADS 256
#define REPS 8   // DIAGNOSTIC: x8 body repetition to force kernel into rocprof
                 // top-5 (cutoff ~43us) and calibrate body cost vs harness
                 // overhead. Results identical each rep; last one stored.

__global__ __launch_bounds__(NTHREADS) void lbp_fwd(
    const float* __restrict__ xg,     // (8,32,64,64) f32
    const float* __restrict__ rawg,   // (4,8,2) f32
    const float* __restrict__ pwg,    // (4,8) f32
    float* __restrict__ outg)         // (8,128,64,64) f32
{
    const int C = 32, H = 64, P = 4, N = 8;
    const int RO = 8;                  // rows owned per block

    __shared__ float2 pair[13][64];    // 8 owned rows + up to 5 halo rows
    __shared__ float2 offs[32];
    __shared__ float  wgt[32];

    int bid = blockIdx.x;
    int s = bid & 7;                   // row-band
    int c = (bid >> 3) & (C - 1);
    int b = bid >> 8;
    int r0 = s * RO;
    int lo = max(0, r0 - 2);
    int hi = min(H, r0 + RO + 3);
    int rows = hi - lo;

    int tid = threadIdx.x;

    if (tid < P * N) {
        float rx = rawg[2 * tid];
        float ry = rawg[2 * tid + 1];
        float ox = 2.0f * (float)tanh((double)(rx * 0.5f));
        float oy = 2.0f * (float)tanh((double)(ry * 0.5f));
        ox = fminf(fmaxf(ox, -2.0f), 2.0f);
        oy = fminf(fmaxf(oy, -2.0f), 2.0f);
        offs[tid] = make_float2(ox, oy);
        wgt[tid]  = pwg[tid];
    }

    const float* xp = xg + (((b * C) + c) << 12);
    for (int idx = tid; idx < rows * 64; idx += NTHREADS) {
        int y = idx >> 6, xx = idx & 63;
        const float* rowp = xp + ((lo + y) << 6);
        float a  = rowp[xx];
        float bb = rowp[min(xx + 1, 63)];
        pair[y][xx] = make_float2(a, bb);
    }
    __syncthreads();

    int w  = tid & 63;
    int hb = tid >> 6;
    float wf = (float)w;

    float xc[2], hf[2];
    int   hrow[2];
    #pragma unroll
    for (int k = 0; k < 2; ++k) {
        int h = r0 + (hb << 1) + k;
        hrow[k] = h;
        hf[k]   = (float)h;
        xc[k]   = pair[h - lo][w].x;
    }

    float accs[4][2];

    #pragma unroll 1
    for (int rep = 0; rep < REPS; ++rep) {
        // Opaque zero: compiler cannot fold it, so every rep's coordinate
        // chain (and everything downstream: addresses, LDS reads, interp)
        // must be re-executed. Numerically +0.0f is exact identity.
        float zf;
        asm volatile("v_mov_b32 %0, 0" : "=v"(zf));
        float wfz = wf + zf;
        float hfz0 = hf[0] + zf;
        float hfz1 = hf[1] + zf;
        float hfz[2] = {hfz0, hfz1};

        for (int p = 0; p < P; ++p) {
            float acc[2] = {0.f, 0.f};
            #pragma unroll 2
            for (int j = 0; j < N; ++j) {
                int pn = p * N + j;
                float2 o = offs[pn];
                float wg = wgt[pn];
                float px   = fminf(fmaxf(__fadd_rn(wfz, o.x), 0.0f), 63.0f);
                float x0f  = floorf(px);
                float wx   = __fsub_rn(px, x0f);
                float omwx = __fsub_rn(1.0f, wx);
                int   x0i  = (int)x0f;
                #pragma unroll
                for (int k = 0; k < 2; ++k) {
                    float py   = fminf(fmaxf(__fadd_rn(hfz[k], o.y), 0.0f), 63.0f);
                    float y0f  = floorf(py);
                    float wy   = __fsub_rn(py, y0f);
                    float omwy = __fsub_rn(1.0f, wy);
                    int   y0i  = (int)y0f;
                    int   y1i  = min(y0i + 1, 63);
                    float2 rv0 = pair[y0i - lo][x0i];
                    float2 rv1 = pair[y1i - lo][x0i];
                    float gx0 = __fadd_rn(__fmul_rn(rv0.x, omwx), __fmul_rn(rv0.y, wx));
                    float gx1 = __fadd_rn(__fmul_rn(rv1.x, omwx), __fmul_rn(rv1.y, wx));
                    float sam = __fadd_rn(__fmul_rn(gx0, omwy), __fmul_rn(gx1, wy));
                    float diff = __fsub_rn(sam, xc[k]);
                    acc[k] += (diff > 0.0f) ? wg : 0.0f;
                }
            }
            // Keep THIS rep's results live so reps 0..REPS-2 aren't dead code.
            asm volatile("" :: "v"(acc[0]), "v"(acc[1]));
            accs[p][0] = acc[0];
            accs[p][1] = acc[1];
        }
    }

    for (int p = 0; p < P; ++p) {
        unsigned int obase = (((unsigned)(b * P + p) * C + c) << 12);
        #pragma unroll
        for (int k = 0; k < 2; ++k) {
            outg[obase + (hrow[k] << 6) + w] = accs[p][k];
        }
    }
}

extern "C" void kernel_launch(void* const* d_in, const int* in_sizes, int n_in,
                              void* d_out, int out_size, void* d_ws, size_t ws_size,
                              hipStream_t stream) {
    const float* x   = (const float*)d_in[0];
    const float* raw = (const float*)d_in[1];
    const float* pw  = (const float*)d_in[2];
    float* out = (float*)d_out;
    (void)in_sizes; (void)n_in; (void)out_size; (void)d_ws; (void)ws_size;

    dim3 grid(8 * 32 * 8);   // B * C * SPLIT
    dim3 block(NTHREADS);
    hipLaunchKernelGGL(lbp_fwd, grid, block, 0, stream, x, raw, pw, out);
}

// Round 11
// 82.794 us; speedup vs baseline: 2.4800x; 2.4800x over previous
//
#include <hip/hip_runtime.h>
#include <math.h>

#define NTHREADS 256

// Geometry: B=8, C=32, H=W=64, P=4, N=8. All f32. Bit-exact vs reference.
// SPLIT=4: grid 1024 = B*C*4; block owns 16 rows; each wave owns 4 rows
// (wave-uniform h) and each thread computes 4 rows x 4 patterns.
// Wave-uniform interior/border split: rows h in [2,61] cannot hit the
// coordinate clip (|offset| <= 2*tanh(1) ~ 1.53) and y1=y0+1<=63 always,
// so the interior y-side is 5 ops (add,floor,cvt,sub,sub) with no clamps.
// LDS pair tile pair[y][x] = (v[x], v[min(x+1,63)]): one sample = 2x
// ds_read_b64 at addr and addr+512 (fusable to ds_read2st64_b64).
__global__ __launch_bounds__(NTHREADS) void lbp_fwd(
    const float* __restrict__ xg,     // (8,32,64,64) f32
    const float* __restrict__ rawg,   // (4,8,2) f32
    const float* __restrict__ pwg,    // (4,8) f32
    float* __restrict__ outg)         // (8,128,64,64) f32
{
    const int C = 32, H = 64, P = 4, N = 8;
    const int RO = 16;                 // rows owned per block

    __shared__ float2 pair[21][64];    // 16 owned rows + up to 5 halo rows
    __shared__ float4 ctab[32];        // (ox, oy, wg, 0) per pn

    int bid = blockIdx.x;
    int s = bid & 3;                   // row-band
    int c = (bid >> 2) & (C - 1);
    int b = bid >> 7;
    int r0 = s * RO;
    int lo = max(0, r0 - 2);
    int hi = min(H, r0 + RO + 3);
    int rows = hi - lo;

    int tid = threadIdx.x;

    // offsets = clip(2*tanh(raw/2), -2, 2); tanh in double -> f32 (proxy for
    // correctly-rounded np tanh). Identical math to the passing R6 kernel.
    if (tid < P * N) {
        float rx = rawg[2 * tid];
        float ry = rawg[2 * tid + 1];
        float ox = 2.0f * (float)tanh((double)(rx * 0.5f));
        float oy = 2.0f * (float)tanh((double)(ry * 0.5f));
        ox = fminf(fmaxf(ox, -2.0f), 2.0f);
        oy = fminf(fmaxf(oy, -2.0f), 2.0f);
        ctab[tid] = make_float4(ox, oy, pwg[tid], 0.0f);
    }

    // Stage pair tile.
    const float* xp = xg + (((b * C) + c) << 12);
    for (int idx = tid; idx < rows * 64; idx += NTHREADS) {
        int y = idx >> 6, xx = idx & 63;
        const float* rowp = xp + ((lo + y) << 6);
        float a  = rowp[xx];
        float bb = rowp[min(xx + 1, 63)];
        pair[y][xx] = make_float2(a, bb);
    }
    __syncthreads();

    int w  = tid & 63;
    int hb = tid >> 6;                 // 0..3; wave-uniform
    float wf = (float)w;
    int h0 = r0 + (hb << 2);           // wave's first row; owns h0..h0+3

    float xc[4], hf[4];
    #pragma unroll
    for (int r = 0; r < 4; ++r) {
        hf[r] = (float)(h0 + r);
        xc[r] = pair[h0 + r - lo][w].x;
    }

    // Wave-uniform branch: only (s==0,hb==0) and (s==3,hb==3) hit clip rows.
    bool yborder = (h0 < 2) || (h0 + 3 > 61);

    float accs[4][4];

    if (!yborder) {
        // ---- interior fast path ----
        for (int p = 0; p < P; ++p) {
            float acc[4] = {0.f, 0.f, 0.f, 0.f};
            for (int j = 0; j < N; ++j) {
                float4 cc = ctab[p * N + j];
                // x-side (general, handles per-lane w borders exactly):
                float px   = fminf(fmaxf(__fadd_rn(wf, cc.x), 0.0f), 63.0f);
                float x0f  = floorf(px);
                float wx   = __fsub_rn(px, x0f);
                float omwx = __fsub_rn(1.0f, wx);
                int   x0i  = (int)x0f;
                const float2* col = &pair[0][x0i];
                #pragma unroll
                for (int r = 0; r < 4; ++r) {
                    // y-side, clip-free (h in [2,61] => 0 <= h+oy <= 63 and
                    // y0 <= 62): py = fl(h+oy) exactly as reference computes.
                    float py   = __fadd_rn(hf[r], cc.y);
                    float y0f  = floorf(py);
                    float wy   = __fsub_rn(py, y0f);
                    float omwy = __fsub_rn(1.0f, wy);
                    int   row0 = (int)y0f - lo;
                    float2 rv0 = col[row0 << 6];        // pair[row0][x0i]
                    float2 rv1 = col[(row0 << 6) + 64]; // +512B: fusable read2st64
                    float gx0 = __fadd_rn(__fmul_rn(rv0.x, omwx), __fmul_rn(rv0.y, wx));
                    float gx1 = __fadd_rn(__fmul_rn(rv1.x, omwx), __fmul_rn(rv1.y, wx));
                    float sam = __fadd_rn(__fmul_rn(gx0, omwy), __fmul_rn(gx1, wy));
                    float diff = __fsub_rn(sam, xc[r]);
                    acc[r] += (diff > 0.0f) ? cc.z : 0.0f;
                }
            }
            #pragma unroll
            for (int r = 0; r < 4; ++r) accs[p][r] = acc[r];
        }
    } else {
        // ---- border path: full general form (bit-exact, same as R6) ----
        for (int p = 0; p < P; ++p) {
            float acc[4] = {0.f, 0.f, 0.f, 0.f};
            for (int j = 0; j < N; ++j) {
                float4 cc = ctab[p * N + j];
                float px   = fminf(fmaxf(__fadd_rn(wf, cc.x), 0.0f), 63.0f);
                float x0f  = floorf(px);
                float wx   = __fsub_rn(px, x0f);
                float omwx = __fsub_rn(1.0f, wx);
                int   x0i  = (int)x0f;
                #pragma unroll
                for (int r = 0; r < 4; ++r) {
                    float py   = fminf(fmaxf(__fadd_rn(hf[r], cc.y), 0.0f), 63.0f);
                    float y0f  = floorf(py);
                    float wy   = __fsub_rn(py, y0f);
                    float omwy = __fsub_rn(1.0f, wy);
                    int   y0i  = (int)y0f;
                    int   y1i  = min(y0i + 1, 63);
                    float2 rv0 = pair[y0i - lo][x0i];
                    float2 rv1 = pair[y1i - lo][x0i];
                    float gx0 = __fadd_rn(__fmul_rn(rv0.x, omwx), __fmul_rn(rv0.y, wx));
                    float gx1 = __fadd_rn(__fmul_rn(rv1.x, omwx), __fmul_rn(rv1.y, wx));
                    float sam = __fadd_rn(__fmul_rn(gx0, omwy), __fmul_rn(gx1, wy));
                    float diff = __fsub_rn(sam, xc[r]);
                    acc[r] += (diff > 0.0f) ? cc.z : 0.0f;
                }
            }
            #pragma unroll
            for (int r = 0; r < 4; ++r) accs[p][r] = acc[r];
        }
    }

    for (int p = 0; p < P; ++p) {
        unsigned int obase = (((unsigned)(b * P + p) * C + c) << 12);
        #pragma unroll
        for (int r = 0; r < 4; ++r) {
            outg[obase + ((unsigned)(h0 + r) << 6) + w] = accs[p][r];
        }
    }
}

extern "C" void kernel_launch(void* const* d_in, const int* in_sizes, int n_in,
                              void* d_out, int out_size, void* d_ws, size_t ws_size,
                              hipStream_t stream) {
    const float* x   = (const float*)d_in[0];
    const float* raw = (const float*)d_in[1];
    const float* pw  = (const float*)d_in[2];
    float* out = (float*)d_out;
    (void)in_sizes; (void)n_in; (void)out_size; (void)d_ws; (void)ws_size;

    dim3 grid(8 * 32 * 4);   // B * C * SPLIT
    dim3 block(NTHREADS);
    hipLaunchKernelGGL(lbp_fwd, grid, block, 0, stream, x, raw, pw, out);
}

// Round 17
// 78.020 us; speedup vs baseline: 2.6318x; 1.0612x over previous
//
#include <hip/hip_runtime.h>
#include <math.h>

#define NTHREADS 256

// Geometry: B=8, C=32, H=W=64, P=4, N=8. All f32. Bit-exact vs reference.
// SPLIT=4: grid 1024; block owns 16 rows; each wave owns 4 rows (uniform h).
// y-side (wy, omwy, row-offsets) is wave-uniform per (pn,row): precomputed
// once per wave into LDS ytab (128 tuples, 2 per lane), general clipped form
// -> single uniform inner path, ~15 VALU + 3 DS per sample.
// LDS pair tile pair[y][x] = (v[x], v[min(x+1,63)]): row read = 1 ds_read_b64.
__global__ __launch_bounds__(NTHREADS) void lbp_fwd(
    const float* __restrict__ xg,     // (8,32,64,64) f32
    const float* __restrict__ rawg,   // (4,8,2) f32
    const float* __restrict__ pwg,    // (4,8) f32
    float* __restrict__ outg)         // (8,128,64,64) f32
{
    const int C = 32, P = 4, N = 8;
    const int RO = 16;                 // rows owned per block

    __shared__ float2 pair[21][64];    // 16 owned rows + up to 5 halo rows
    __shared__ float2 ctab[32];        // (ox, wg) per pn
    __shared__ uint4  ytab[4][128];    // per wave: [pn*4+r] = (wy, omwy, off0, off1)

    int bid = blockIdx.x;
    int s = bid & 3;                   // row-band
    int c = (bid >> 2) & (C - 1);
    int b = bid >> 7;
    int r0 = s * RO;
    int lo = max(0, r0 - 2);
    int hi = min(64, r0 + RO + 3);
    int rows = hi - lo;

    int tid = threadIdx.x;
    int w   = tid & 63;
    int hb  = tid >> 6;                // wave id 0..3; wave-uniform
    int h0  = r0 + (hb << 2);          // wave's first row

    // ctab: ox = clip(2*tanh(rawx/2)) and weight. tanh in double -> f32
    // (proxy for correctly-rounded np tanh), as in all passing rounds.
    if (tid < P * N) {
        float rx = rawg[2 * tid];
        float ox = 2.0f * (float)tanh((double)(rx * 0.5f));
        ox = fminf(fmaxf(ox, -2.0f), 2.0f);
        ctab[tid] = make_float2(ox, pwg[tid]);
    }

    // ytab precompute: lane l of wave hb computes tuples T=l and T=l+64,
    // T = pn*4 + r. Full general clipped y-form, bit-identical to reference.
    {
        int pn0 = w >> 2;              // 0..15
        int r   = w & 3;
        float hf = (float)(h0 + r);
        #pragma unroll
        for (int half = 0; half < 2; ++half) {
            int pn = pn0 + half * 16;
            float ry = rawg[2 * pn + 1];
            float oy = 2.0f * (float)tanh((double)(ry * 0.5f));
            oy = fminf(fmaxf(oy, -2.0f), 2.0f);
            float py   = fminf(fmaxf(__fadd_rn(hf, oy), 0.0f), 63.0f);
            float y0f  = floorf(py);
            float wy   = __fsub_rn(py, y0f);
            float omwy = __fsub_rn(1.0f, wy);
            int   y0i  = (int)y0f;
            int   y1i  = min(y0i + 1, 63);
            uint4 t;
            t.x = __float_as_uint(wy);
            t.y = __float_as_uint(omwy);
            t.z = (unsigned)((y0i - lo) << 9);   // byte offset of pair row
            t.w = (unsigned)((y1i - lo) << 9);
            ytab[hb][(pn << 2) + r] = t;
        }
    }

    // Stage pair tile.
    const float* xp = xg + (((b * C) + c) << 12);
    for (int idx = tid; idx < rows * 64; idx += NTHREADS) {
        int y = idx >> 6, xx = idx & 63;
        const float* rowp = xp + ((lo + y) << 6);
        float a  = rowp[xx];
        float bb = rowp[min(xx + 1, 63)];
        pair[y][xx] = make_float2(a, bb);
    }
    __syncthreads();

    float wf = (float)w;
    float xc[4];
    #pragma unroll
    for (int r = 0; r < 4; ++r) xc[r] = pair[h0 + r - lo][w].x;

    const char* tb = (const char*)&pair[0][0];
    const uint4* yt = &ytab[hb][0];

    float accs[4][4];

    for (int p = 0; p < P; ++p) {
        float acc[4] = {0.f, 0.f, 0.f, 0.f};
        #pragma unroll 2
        for (int j = 0; j < N; ++j) {
            int pn = p * N + j;
            float2 cc = ctab[pn];
            // x-side (general; per-lane borders exact):
            float px   = fminf(fmaxf(__fadd_rn(wf, cc.x), 0.0f), 63.0f);
            float x0f  = floorf(px);
            float wx   = __fsub_rn(px, x0f);
            float omwx = __fsub_rn(1.0f, wx);
            unsigned xoff = ((unsigned)(int)x0f) << 3;   // byte offset in row
            const uint4* ytp = yt + (pn << 2);
            #pragma unroll
            for (int r = 0; r < 4; ++r) {
                uint4 t = ytp[r];                    // b128 broadcast read
                float wy   = __uint_as_float(t.x);
                float omwy = __uint_as_float(t.y);
                float2 rv0 = *(const float2*)(tb + (t.z + xoff));
                float2 rv1 = *(const float2*)(tb + (t.w + xoff));
                // Exact reference op order, no FMA contraction:
                float gx0 = __fadd_rn(__fmul_rn(rv0.x, omwx), __fmul_rn(rv0.y, wx));
                float gx1 = __fadd_rn(__fmul_rn(rv1.x, omwx), __fmul_rn(rv1.y, wx));
                float sam = __fadd_rn(__fmul_rn(gx0, omwy), __fmul_rn(gx1, wy));
                float diff = __fsub_rn(sam, xc[r]);
                acc[r] += (diff > 0.0f) ? cc.y : 0.0f;   // forward == b_hard
            }
        }
        #pragma unroll
        for (int r = 0; r < 4; ++r) accs[p][r] = acc[r];
    }

    for (int p = 0; p < P; ++p) {
        unsigned int obase = (((unsigned)(b * P + p) * C + c) << 12);
        #pragma unroll
        for (int r = 0; r < 4; ++r) {
            outg[obase + ((unsigned)(h0 + r) << 6) + w] = accs[p][r];
        }
    }
}

extern "C" void kernel_launch(void* const* d_in, const int* in_sizes, int n_in,
                              void* d_out, int out_size, void* d_ws, size_t ws_size,
                              hipStream_t stream) {
    const float* x   = (const float*)d_in[0];
    const float* raw = (const float*)d_in[1];
    const float* pw  = (const float*)d_in[2];
    float* out = (float*)d_out;
    (void)in_sizes; (void)n_in; (void)out_size; (void)d_ws; (void)ws_size;

    dim3 grid(8 * 32 * 4);   // B * C * SPLIT
    dim3 block(NTHREADS);
    hipLaunchKernelGGL(lbp_fwd, grid, block, 0, stream, x, raw, pw, out);
}